// Round 3
// baseline (873.455 us; speedup 1.0000x reference)
//
#include <hip/hip_runtime.h>
#include <math.h>

typedef __attribute__((ext_vector_type(4))) float f32x4;
typedef __attribute__((ext_vector_type(8))) short bf16x8;

namespace {
constexpr int B_ = 4, C_ = 512, N_ = 4096;
constexpr int JT  = 64;            // query columns per WG
constexpr int IB  = 128;           // key rows per flash iteration
constexpr int KC  = 32;            // channel chunk staged in LDS
constexpr int NCH = C_ / KC;       // 16
constexpr int NIB = N_ / IB;       // 32
}

__device__ __forceinline__ unsigned short f2bf(float f) {
    unsigned int u = __float_as_uint(f);
    u = (u + 0x7fffu + ((u >> 16) & 1u)) >> 16;
    return (unsigned short)u;
}
__device__ __forceinline__ float bf2f(unsigned short h) {
    return __uint_as_float(((unsigned int)h) << 16);
}

// async global->LDS, 16 B per lane; LDS dest is wave-uniform base + lane*16
__device__ __forceinline__ void gll16(const unsigned short* g, unsigned short* l) {
    __builtin_amdgcn_global_load_lds(
        (const __attribute__((address_space(1))) void*)g,
        (__attribute__((address_space(3))) void*)l, 16, 0, 0);
}

// ---------- pre-pass 1: X[b][c][i] (f32) -> Xt hi/lo [b][i][c] (bf16 split) ----------
__global__ __launch_bounds__(256)
void cvt_transpose_split(const float* __restrict__ X,
                         unsigned short* __restrict__ Xh,
                         unsigned short* __restrict__ Xl)
{
    __shared__ float tile[64][66];
    const int t   = (int)threadIdx.x;
    const int blk = (int)blockIdx.x;
    const int b   = blk >> 9;
    const int r   = blk & 511;
    const int it  = r >> 3;
    const int ct  = r & 7;

    const float* src = X + ((size_t)(b * C_ + ct * 64)) * N_ + it * 64;
    #pragma unroll
    for (int rep = 0; rep < 4; ++rep) {
        int idx = rep * 256 + t;
        int c   = idx >> 4;
        int i4  = (idx & 15) * 4;
        const float4 v = *(const float4*)(src + (size_t)c * N_ + i4);
        tile[c][i4 + 0] = v.x; tile[c][i4 + 1] = v.y;
        tile[c][i4 + 2] = v.z; tile[c][i4 + 3] = v.w;
    }
    __syncthreads();
    unsigned short* dh = Xh + ((size_t)(b * N_ + it * 64)) * C_ + ct * 64;
    unsigned short* dl = Xl + ((size_t)(b * N_ + it * 64)) * C_ + ct * 64;
    #pragma unroll
    for (int rep = 0; rep < 4; ++rep) {
        int idx = rep * 256 + t;
        int i   = idx >> 4;
        int c4  = (idx & 15) * 4;
        ushort4 hv, lv;
        {
            float f0 = tile[c4 + 0][i], f1 = tile[c4 + 1][i];
            float f2 = tile[c4 + 2][i], f3 = tile[c4 + 3][i];
            hv.x = f2bf(f0); lv.x = f2bf(f0 - bf2f(hv.x));
            hv.y = f2bf(f1); lv.y = f2bf(f1 - bf2f(hv.y));
            hv.z = f2bf(f2); lv.z = f2bf(f2 - bf2f(hv.z));
            hv.w = f2bf(f3); lv.w = f2bf(f3 - bf2f(hv.w));
        }
        *(ushort4*)(dh + (size_t)i * C_ + c4) = hv;
        *(ushort4*)(dl + (size_t)i * C_ + c4) = lv;
    }
}

// ---------- pre-pass 2: V (f32) -> V hi (bf16), same [b][c][i] layout ----------
__global__ __launch_bounds__(256)
void cvt_split_hi(const float* __restrict__ X, unsigned short* __restrict__ Xh)
{
    size_t base = ((size_t)blockIdx.x * 256 + threadIdx.x) * 16;
    #pragma unroll
    for (int g = 0; g < 2; ++g) {
        float4 a = *(const float4*)(X + base + g * 8);
        float4 c = *(const float4*)(X + base + g * 8 + 4);
        ushort4 h0, h1;
        h0.x = f2bf(a.x); h0.y = f2bf(a.y); h0.z = f2bf(a.z); h0.w = f2bf(a.w);
        h1.x = f2bf(c.x); h1.y = f2bf(c.y); h1.z = f2bf(c.z); h1.w = f2bf(c.w);
        *(ushort4*)(Xh + base + g * 8)     = h0;
        *(ushort4*)(Xh + base + g * 8 + 4) = h1;
    }
}

// ---------- main fused flash-attention kernel ----------
// 8 waves: iw = w&3 (i-range), jw = w>>2 (j-half) for phase A.
// K/Q LDS layout: interleaved-pair rows: memrow m = idx>>1, 128 B rows of
// [even idx 32ch | odd idx 32ch], quad-in-row XOR-swizzled by (m&7).
__global__ __launch_bounds__(512, 4)
void attn_mfma2(const unsigned short* __restrict__ Kth,
                const unsigned short* __restrict__ Ktl,
                const unsigned short* __restrict__ Qth,
                const unsigned short* __restrict__ Qtl,
                const unsigned short* __restrict__ Vh,
                const float* __restrict__ Qorig,
                float* __restrict__ Out)
{
    __shared__ unsigned short KhL[2][4096];   // 8 KB per buf (64 memrows x 128 B)
    __shared__ unsigned short KlL[2][4096];
    __shared__ unsigned short QhL[2][2048];   // 4 KB per buf (32 memrows)
    __shared__ unsigned short QlL[2][2048];
    __shared__ unsigned short Pt[JT * IB];    // 16 KB, XOR-swizzled [j][i] bf16
    __shared__ float m_lds[JT], l_lds[JT], scale_lds[JT];
    __shared__ float red_max[4][JT], red_sum[4][JT];

    const int t    = (int)threadIdx.x;
    const int w    = t >> 6;
    const int lane = t & 63;
    const int lr   = lane & 15;
    const int lg   = lane >> 4;
    const int iw   = w & 3;
    const int jw   = w >> 2;

    // XCD-aware swizzle (256 = 8 XCD * 32, bijective)
    const int bidl = ((int)blockIdx.x & 7) * 32 + ((int)blockIdx.x >> 3);
    const int b    = bidl >> 6;
    const int j0   = (bidl & 63) * JT;
    const int bN   = b * N_;

    // precomputed fragment byte-offsets within one K/Q buffer
    int offK[2], offQ[2];
    #pragma unroll
    for (int it = 0; it < 2; ++it) {
        const int i = iw * 32 + it * 16 + lr, m = i >> 1;
        offK[it] = m * 128 + (((((i & 1) << 2) + lg) ^ (m & 7)) << 4);
    }
    #pragma unroll
    for (int jt = 0; jt < 2; ++jt) {
        const int j = jw * 32 + jt * 16 + lr, m = j >> 1;
        offQ[jt] = m * 128 + (((((j & 1) << 2) + lg) ^ (m & 7)) << 4);
    }

    // stage one 32-channel chunk (K 16 KB + Q 8 KB) into buffer db: 24 gll
    // calls, 3 per wave. Per-lane GLOBAL address is pre-swizzled so the
    // linear LDS destination holds the swizzled layout (T21).
    auto stage = [&](int i0s, int c0s, int db) {
        #pragma unroll
        for (int r = 0; r < 3; ++r) {
            const int call = w * 3 + r;
            if (call < 16) {                       // Kh: 0..7, Kl: 8..15
                const int cl = call & 7;
                const int qg = cl * 64 + lane;     // 0..511
                const int m  = qg >> 3;
                const int qr = (qg & 7) ^ (m & 7);
                const int i  = 2 * m + (qr >> 2);
                const int cq = (qr & 3) * 8;
                const unsigned short* src =
                    (call < 8 ? Kth : Ktl) + ((size_t)(bN + i0s + i)) * C_ + c0s + cq;
                gll16(src, (call < 8 ? KhL[db] : KlL[db]) + cl * 512);
            } else {                               // Qh: 16..19, Ql: 20..23
                const int cl  = call - 16;
                const int arr = cl >> 2;
                const int c2  = cl & 3;
                const int qg  = c2 * 64 + lane;    // 0..255
                const int m   = qg >> 3;
                const int qr  = (qg & 7) ^ (m & 7);
                const int j   = 2 * m + (qr >> 2);
                const int cq  = (qr & 3) * 8;
                const unsigned short* src =
                    (arr == 0 ? Qth : Qtl) + ((size_t)(bN + j0 + j)) * C_ + c0s + cq;
                gll16(src, (arr == 0 ? QhL[db] : QlL[db]) + c2 * 512);
            }
        }
    };

    if (t < JT) { m_lds[t] = -INFINITY; l_lds[t] = 0.0f; }

    f32x4 Oacc[4][4];
    #pragma unroll
    for (int a = 0; a < 4; ++a)
        #pragma unroll
        for (int c = 0; c < 4; ++c) Oacc[a][c] = (f32x4)0.0f;

    stage(0, 0, 0);            // prologue: (ib0, ck0) -> buf 0
    __syncthreads();           // drains vmcnt + lgkm

    for (int ib = 0; ib < NIB; ++ib) {
        const int i0 = ib * IB;

        f32x4 Sacc[2][2];
        #pragma unroll
        for (int x = 0; x < 2; ++x)
            #pragma unroll
            for (int y = 0; y < 2; ++y) Sacc[x][y] = (f32x4)0.0f;

        // ---- phase A: S += K^T Q, 16 chunks, 1 barrier each ----
        for (int ck = 0; ck < NCH; ++ck) {
            const int d = ck & 1;
            if (ck + 1 < NCH) stage(i0, (ck + 1) * KC, d ^ 1);

            const char* kh = (const char*)KhL[d];
            const char* kl = (const char*)KlL[d];
            const char* qh = (const char*)QhL[d];
            const char* ql = (const char*)QlL[d];

            bf16x8 bqh[2], bql[2];
            #pragma unroll
            for (int jt = 0; jt < 2; ++jt) {
                bqh[jt] = *(const bf16x8*)(qh + offQ[jt]);
                bql[jt] = *(const bf16x8*)(ql + offQ[jt]);
            }
            #pragma unroll
            for (int it = 0; it < 2; ++it) {
                const bf16x8 akh = *(const bf16x8*)(kh + offK[it]);
                const bf16x8 akl = *(const bf16x8*)(kl + offK[it]);
                #pragma unroll
                for (int jt = 0; jt < 2; ++jt) {
                    Sacc[it][jt] = __builtin_amdgcn_mfma_f32_16x16x32_bf16(akh, bqh[jt], Sacc[it][jt], 0, 0, 0);
                    Sacc[it][jt] = __builtin_amdgcn_mfma_f32_16x16x32_bf16(akh, bql[jt], Sacc[it][jt], 0, 0, 0);
                    Sacc[it][jt] = __builtin_amdgcn_mfma_f32_16x16x32_bf16(akl, bqh[jt], Sacc[it][jt], 0, 0, 0);
                }
            }
            __syncthreads();
        }

        // ---- (a) per-column block max ----
        #pragma unroll
        for (int jt = 0; jt < 2; ++jt) {
            float mx = -INFINITY;
            #pragma unroll
            for (int it = 0; it < 2; ++it)
                #pragma unroll
                for (int r = 0; r < 4; ++r) mx = fmaxf(mx, Sacc[it][jt][r]);
            mx = fmaxf(mx, __shfl_xor(mx, 16));
            mx = fmaxf(mx, __shfl_xor(mx, 32));
            if (lane < 16) red_max[iw][jw * 32 + jt * 16 + lane] = mx;
        }
        __syncthreads();

        // ---- (b) running max + rescale factor ----
        if (t < JT) {
            const float m_old = m_lds[t];
            float bm = fmaxf(fmaxf(red_max[0][t], red_max[1][t]),
                             fmaxf(red_max[2][t], red_max[3][t]));
            const float m_new = fmaxf(m_old, bm);
            m_lds[t] = m_new;
            scale_lds[t] = __expf(m_old - m_new);
        }
        __syncthreads();

        // ---- (c) exp, P -> LDS (swizzled), column partial sums, O-rescale ----
        #pragma unroll
        for (int jt = 0; jt < 2; ++jt) {
            const int j = jw * 32 + jt * 16 + lr;
            const float mcol = m_lds[j];
            float csum = 0.0f;
            #pragma unroll
            for (int it = 0; it < 2; ++it) {
                const float p0 = __expf(Sacc[it][jt][0] - mcol);
                const float p1 = __expf(Sacc[it][jt][1] - mcol);
                const float p2 = __expf(Sacc[it][jt][2] - mcol);
                const float p3 = __expf(Sacc[it][jt][3] - mcol);
                csum += (p0 + p1) + (p2 + p3);
                ushort4 pk;
                pk.x = f2bf(p0); pk.y = f2bf(p1); pk.z = f2bf(p2); pk.w = f2bf(p3);
                const int i = iw * 32 + it * 16 + lg * 4;
                const unsigned byteoff =
                    ((unsigned)(j * (IB * 2) + i * 2)) ^ (((unsigned)(j & 7)) << 4);
                *(ushort4*)((char*)Pt + byteoff) = pk;
            }
            csum += __shfl_xor(csum, 16);
            csum += __shfl_xor(csum, 32);
            if (lane < 16) red_sum[iw][j] = csum;
        }
        {
            float scj[4];
            #pragma unroll
            for (int jt = 0; jt < 4; ++jt) scj[jt] = scale_lds[jt * 16 + lr];
            #pragma unroll
            for (int ct = 0; ct < 4; ++ct)
                #pragma unroll
                for (int jt = 0; jt < 4; ++jt) {
                    Oacc[ct][jt][0] *= scj[jt];
                    Oacc[ct][jt][1] *= scj[jt];
                    Oacc[ct][jt][2] *= scj[jt];
                    Oacc[ct][jt][3] *= scj[jt];
                }
        }
        __syncthreads();

        // ---- (d) running denominator ----
        if (t < JT)
            l_lds[t] = l_lds[t] * scale_lds[t] +
                       (red_sum[0][t] + red_sum[1][t]) + (red_sum[2][t] + red_sum[3][t]);

        // ---- phase B: Oacc += V_block * P; prefetch next i-block chunk 0 ----
        if (ib + 1 < NIB) stage((ib + 1) * IB, 0, 0);
        {
            const int c0w = w * 64;
            #pragma unroll
            for (int ks = 0; ks < 4; ++ks) {
                bf16x8 pf[4];
                #pragma unroll
                for (int jt = 0; jt < 4; ++jt) {
                    const int j = jt * 16 + lr;
                    const unsigned byteoff =
                        ((unsigned)(j * (IB * 2) + ks * 64 + lg * 16)) ^ (((unsigned)(j & 7)) << 4);
                    pf[jt] = *(const bf16x8*)((char*)Pt + byteoff);
                }
                #pragma unroll
                for (int ct = 0; ct < 4; ++ct) {
                    const int c = c0w + ct * 16 + lr;
                    const bf16x8 vf =
                        *(const bf16x8*)(Vh + ((size_t)(b * C_ + c)) * N_ + i0 + ks * 32 + lg * 8);
                    #pragma unroll
                    for (int jt = 0; jt < 4; ++jt)
                        Oacc[ct][jt] = __builtin_amdgcn_mfma_f32_16x16x32_bf16(vf, pf[jt], Oacc[ct][jt], 0, 0, 0);
                }
            }
        }
        __syncthreads();   // Pt reads drained; staged chunk0 ready; l_lds visible
    }

    // ---- epilogue: out = q + Oacc / l ----
    {
        float il[4];
        #pragma unroll
        for (int jt = 0; jt < 4; ++jt) il[jt] = 1.0f / l_lds[jt * 16 + lr];
        const int c0w = w * 64;
        #pragma unroll
        for (int ct = 0; ct < 4; ++ct) {
            #pragma unroll
            for (int r = 0; r < 4; ++r) {
                const int c = c0w + ct * 16 + lg * 4 + r;
                const float* qrow = Qorig + ((size_t)(b * C_ + c)) * N_ + j0;
                float*       orow = Out   + ((size_t)(b * C_ + c)) * N_ + j0;
                #pragma unroll
                for (int jt = 0; jt < 4; ++jt) {
                    const int j = jt * 16 + lr;
                    orow[j] = qrow[j] + Oacc[ct][jt][r] * il[jt];
                }
            }
        }
    }
}

// ---------- fallback (round-1 f32 kernel) if workspace is too small ----------
namespace {
constexpr int FJT = 32, FIB = 64, FTPB = 256, FNJT = N_ / FJT;
}
__global__ __launch_bounds__(FTPB, 2)
void attn_fused_f32(const float* __restrict__ Q,
                    const float* __restrict__ K,
                    const float* __restrict__ V,
                    float* __restrict__ O)
{
    __shared__ float q_lds[C_][FJT];
    __shared__ float p_t[FJT][FIB + 4];
    __shared__ float red_max[8][FJT];
    __shared__ float red_sum[8][FJT];

    const int t  = (int)threadIdx.x;
    const int j  = t & (FJT - 1);
    const int g  = t >> 5;
    const int b  = (int)blockIdx.x / FNJT;
    const int j0 = ((int)blockIdx.x % FNJT) * FJT;

    const float* Qb = Q + ((size_t)b * C_) * N_ + j0;
    const float* Kb = K + ((size_t)b * C_) * N_;
    const float* Vb = V + ((size_t)b * C_) * N_;
    float*       Ob = O + ((size_t)b * C_) * N_ + j0;

    #pragma unroll 4
    for (int r = 0; r < (C_ * FJT) / FTPB; ++r) {
        int idx = r * FTPB + t;
        q_lds[idx >> 5][idx & (FJT - 1)] = Qb[(size_t)(idx >> 5) * N_ + (idx & (FJT - 1))];
    }
    __syncthreads();

    float acc[64];
    #pragma unroll
    for (int x = 0; x < 64; ++x) acc[x] = 0.0f;
    float m_run = -INFINITY, l_run = 0.0f;

    for (int i0 = 0; i0 < N_; i0 += FIB) {
        float s_acc[8];
        #pragma unroll
        for (int r = 0; r < 8; ++r) s_acc[r] = 0.0f;
        const float* kp = Kb + i0 + g * 8;
        #pragma unroll 4
        for (int c = 0; c < C_; ++c) {
            float qv = q_lds[c][j];
            const float4 k0 = *(const float4*)(kp + (size_t)c * N_);
            const float4 k1 = *(const float4*)(kp + (size_t)c * N_ + 4);
            s_acc[0] = fmaf(k0.x, qv, s_acc[0]); s_acc[1] = fmaf(k0.y, qv, s_acc[1]);
            s_acc[2] = fmaf(k0.z, qv, s_acc[2]); s_acc[3] = fmaf(k0.w, qv, s_acc[3]);
            s_acc[4] = fmaf(k1.x, qv, s_acc[4]); s_acc[5] = fmaf(k1.y, qv, s_acc[5]);
            s_acc[6] = fmaf(k1.z, qv, s_acc[6]); s_acc[7] = fmaf(k1.w, qv, s_acc[7]);
        }
        float tmax = fmaxf(fmaxf(fmaxf(s_acc[0], s_acc[1]), fmaxf(s_acc[2], s_acc[3])),
                           fmaxf(fmaxf(s_acc[4], s_acc[5]), fmaxf(s_acc[6], s_acc[7])));
        red_max[g][j] = tmax;
        __syncthreads();
        float bmax = red_max[0][j];
        #pragma unroll
        for (int gg = 1; gg < 8; ++gg) bmax = fmaxf(bmax, red_max[gg][j]);
        float new_m = fmaxf(m_run, bmax);
        float scale = __expf(m_run - new_m);
        float psum = 0.0f, pv[8];
        #pragma unroll
        for (int r = 0; r < 8; ++r) { pv[r] = __expf(s_acc[r] - new_m); psum += pv[r]; }
        #pragma unroll
        for (int r = 0; r < 8; ++r) p_t[j][g * 8 + r] = pv[r];
        red_sum[g][j] = psum;
        __syncthreads();
        float bsum = 0.0f;
        #pragma unroll
        for (int gg = 0; gg < 8; ++gg) bsum += red_sum[gg][j];
        l_run = l_run * scale + bsum;
        m_run = new_m;
        #pragma unroll
        for (int x = 0; x < 64; ++x) acc[x] *= scale;
        const float* vp = Vb + (size_t)(g * 64) * N_ + i0;
        for (int i4 = 0; i4 < 16; ++i4) {
            const float4 p4 = *(const float4*)&p_t[j][i4 * 4];
            const float* vpi = vp + i4 * 4;
            #pragma unroll
            for (int cq = 0; cq < 4; ++cq) {
                #pragma unroll
                for (int ci = 0; ci < 16; ++ci) {
                    const int cc = cq * 16 + ci;
                    const float4 vv = *(const float4*)(vpi + (size_t)cc * N_);
                    acc[cc] = fmaf(vv.x, p4.x, acc[cc]);
                    acc[cc] = fmaf(vv.y, p4.y, acc[cc]);
                    acc[cc] = fmaf(vv.z, p4.z, acc[cc]);
                    acc[cc] = fmaf(vv.w, p4.w, acc[cc]);
                }
                asm volatile("" ::: "memory");
            }
        }
    }
    const float inv_l = 1.0f / l_run;
    #pragma unroll
    for (int cc = 0; cc < 64; ++cc) {
        const int c = g * 64 + cc;
        Ob[(size_t)c * N_ + j] = q_lds[c][j] + acc[cc] * inv_l;
    }
}

extern "C" void kernel_launch(void* const* d_in, const int* in_sizes, int n_in,
                              void* d_out, int out_size, void* d_ws, size_t ws_size,
                              hipStream_t stream) {
    const float* Q = (const float*)d_in[0];
    const float* K = (const float*)d_in[1];
    const float* V = (const float*)d_in[2];
    float* O = (float*)d_out;

    const size_t EL   = (size_t)B_ * C_ * N_;
    const size_t NEED = EL * 2 * 5;            // 5 bf16 arrays = 80 MiB

    if (ws_size >= NEED) {
        unsigned short* Kth = (unsigned short*)d_ws;
        unsigned short* Ktl = Kth + EL;
        unsigned short* Qth = Ktl + EL;
        unsigned short* Qtl = Qth + EL;
        unsigned short* Vhh = Qtl + EL;
        cvt_transpose_split<<<dim3(2048), dim3(256), 0, stream>>>(K, Kth, Ktl);
        cvt_transpose_split<<<dim3(2048), dim3(256), 0, stream>>>(Q, Qth, Qtl);
        cvt_split_hi<<<dim3(2048), dim3(256), 0, stream>>>(V, Vhh);
        attn_mfma2<<<dim3(256), dim3(512), 0, stream>>>(Kth, Ktl, Qth, Qtl, Vhh, Q, O);
    } else {
        attn_fused_f32<<<dim3(B_ * FNJT), dim3(FTPB), 0, stream>>>(Q, K, V, O);
    }
}

// Round 4
// 763.552 us; speedup vs baseline: 1.1439x; 1.1439x over previous
//
#include <hip/hip_runtime.h>
#include <math.h>

typedef __attribute__((ext_vector_type(4))) float f32x4;
typedef __attribute__((ext_vector_type(8))) short bf16x8;
typedef unsigned short ushort_t;

namespace {
constexpr int B_ = 4, C_ = 512, N_ = 4096;
constexpr int JT  = 64;            // query columns per WG
constexpr int IB  = 128;           // key rows per flash iteration
constexpr int KC  = 32;            // channel chunk staged in LDS
constexpr int NCH = C_ / KC;       // 16
constexpr int NIB = N_ / IB;       // 32
}

__device__ __forceinline__ unsigned short f2bf(float f) {
    unsigned int u = __float_as_uint(f);
    u = (u + 0x7fffu + ((u >> 16) & 1u)) >> 16;
    return (unsigned short)u;
}
__device__ __forceinline__ float bf2f(unsigned short h) {
    return __uint_as_float(((unsigned int)h) << 16);
}

// ---------- pre-pass 1: X[b][c][i] (f32) -> Xt hi/lo [b][i][c] (bf16 split) ----------
__global__ __launch_bounds__(256)
void cvt_transpose_split(const float* __restrict__ X,
                         unsigned short* __restrict__ Xh,
                         unsigned short* __restrict__ Xl)
{
    __shared__ float tile[64][66];
    const int t   = (int)threadIdx.x;
    const int blk = (int)blockIdx.x;
    const int b   = blk >> 9;
    const int r   = blk & 511;
    const int it  = r >> 3;
    const int ct  = r & 7;

    const float* src = X + ((size_t)(b * C_ + ct * 64)) * N_ + it * 64;
    #pragma unroll
    for (int rep = 0; rep < 4; ++rep) {
        int idx = rep * 256 + t;
        int c   = idx >> 4;
        int i4  = (idx & 15) * 4;
        const float4 v = *(const float4*)(src + (size_t)c * N_ + i4);
        tile[c][i4 + 0] = v.x; tile[c][i4 + 1] = v.y;
        tile[c][i4 + 2] = v.z; tile[c][i4 + 3] = v.w;
    }
    __syncthreads();
    unsigned short* dh = Xh + ((size_t)(b * N_ + it * 64)) * C_ + ct * 64;
    unsigned short* dl = Xl + ((size_t)(b * N_ + it * 64)) * C_ + ct * 64;
    #pragma unroll
    for (int rep = 0; rep < 4; ++rep) {
        int idx = rep * 256 + t;
        int i   = idx >> 4;
        int c4  = (idx & 15) * 4;
        ushort4 hv, lv;
        {
            float f0 = tile[c4 + 0][i], f1 = tile[c4 + 1][i];
            float f2 = tile[c4 + 2][i], f3 = tile[c4 + 3][i];
            hv.x = f2bf(f0); lv.x = f2bf(f0 - bf2f(hv.x));
            hv.y = f2bf(f1); lv.y = f2bf(f1 - bf2f(hv.y));
            hv.z = f2bf(f2); lv.z = f2bf(f2 - bf2f(hv.z));
            hv.w = f2bf(f3); lv.w = f2bf(f3 - bf2f(hv.w));
        }
        *(ushort4*)(dh + (size_t)i * C_ + c4) = hv;
        *(ushort4*)(dl + (size_t)i * C_ + c4) = lv;
    }
}

// ---------- pre-pass 2: V (f32) -> V hi (bf16), same [b][c][i] layout ----------
__global__ __launch_bounds__(256)
void cvt_split_hi(const float* __restrict__ X, unsigned short* __restrict__ Xh)
{
    size_t base = ((size_t)blockIdx.x * 256 + threadIdx.x) * 16;
    #pragma unroll
    for (int g = 0; g < 2; ++g) {
        float4 a = *(const float4*)(X + base + g * 8);
        float4 c = *(const float4*)(X + base + g * 8 + 4);
        ushort4 h0, h1;
        h0.x = f2bf(a.x); h0.y = f2bf(a.y); h0.z = f2bf(a.z); h0.w = f2bf(a.w);
        h1.x = f2bf(c.x); h1.y = f2bf(c.y); h1.z = f2bf(c.z); h1.w = f2bf(c.w);
        *(ushort4*)(Xh + base + g * 8)     = h0;
        *(ushort4*)(Xh + base + g * 8 + 4) = h1;
    }
}

// ---------- main fused flash-attention kernel (reg-staged, split-i capable) ----------
// grid = 256*nsplit. 8 waves: iw=w&3 (32-row i-strip), jw=w>>2 (32-col j-half).
// K/Q LDS: memrow m=idx>>1, 128B rows [even|odd], 16B-quad XOR-swizzled by (m&7).
__global__ __launch_bounds__(512, 4)
void attn_mfma3(const unsigned short* __restrict__ Kth,
                const unsigned short* __restrict__ Ktl,
                const unsigned short* __restrict__ Qth,
                const unsigned short* __restrict__ Qtl,
                const unsigned short* __restrict__ Vh,
                const float* __restrict__ Qorig,
                float* __restrict__ Out,
                unsigned short* __restrict__ Opart,
                float* __restrict__ ml,
                int nsplit, int niblk)
{
    __shared__ unsigned short KhL[2][4096];   // 8 KB per buf
    __shared__ unsigned short KlL[2][4096];
    __shared__ unsigned short QhL[2][2048];   // 4 KB per buf
    __shared__ unsigned short QlL[2][2048];
    __shared__ unsigned short Pt[JT * IB];    // 16 KB, XOR-swizzled [j][i]
    __shared__ float red_max[4][JT];
    __shared__ float red_sum[4][JT];

    const int t    = (int)threadIdx.x;
    const int w    = t >> 6;
    const int lane = t & 63;
    const int lr   = lane & 15;
    const int lg   = lane >> 4;
    const int iw   = w & 3;
    const int jw   = w >> 2;

    // XCD swizzle: contiguous bidl per XCD so same-(b,s) WGs share L2
    const int nwg  = 256 * nsplit;
    const int q8   = nwg >> 3;
    const int bidl = ((int)blockIdx.x & 7) * q8 + ((int)blockIdx.x >> 3);
    const int s    = bidl >> 8;
    const int pj   = bidl & 255;
    const int b    = pj >> 6;
    const int j0   = (pj & 63) * JT;
    const int bN   = b * N_;
    const int ibase = s * (N_ / nsplit) * 0 + s * (nsplit == 2 ? N_ / 2 : 0);

    // fragment read byte-offsets
    int offK[2], offQ[2];
    #pragma unroll
    for (int it = 0; it < 2; ++it) {
        const int i = iw * 32 + it * 16 + lr, m = i >> 1;
        offK[it] = m * 128 + (((((i & 1) << 2) + lg) ^ (m & 7)) << 4);
    }
    #pragma unroll
    for (int jt = 0; jt < 2; ++jt) {
        const int j = jw * 32 + jt * 16 + lr, m = j >> 1;
        offQ[jt] = m * 128 + (((((j & 1) << 2) + lg) ^ (m & 7)) << 4);
    }

    // staging decomposition + swizzled LDS write offsets (constant per thread)
    const int ist = t >> 2, cst = (t & 3) * 8;    // K: 128 rows x 32 ch, 16B each
    const int jst = t >> 3, cqst = (t & 7) * 4;   // Q: 64 rows x 32 ch, 8B each
    const int mK = ist >> 1;
    const int wKo = mK * 128 + (((((ist & 1) << 2) | (t & 3)) ^ (mK & 7)) << 4);
    const int mQ = jst >> 1;
    const int wQo = mQ * 128 + (((((jst & 1) << 2) | ((t & 7) >> 1)) ^ (mQ & 7)) << 4) + (t & 1) * 8;

    uint4 kh4, kl4; uint2 qh2, ql2;
    auto load = [&](int i0abs, int c0) {
        const size_t kb = ((size_t)(bN + i0abs + ist)) * C_ + c0 + cst;
        kh4 = *(const uint4*)(Kth + kb);
        kl4 = *(const uint4*)(Ktl + kb);
        const size_t qb = ((size_t)(bN + j0 + jst)) * C_ + c0 + cqst;
        qh2 = *(const uint2*)(Qth + qb);
        ql2 = *(const uint2*)(Qtl + qb);
    };
    auto store = [&](int d) {
        *(uint4*)((char*)KhL[d] + wKo) = kh4;
        *(uint4*)((char*)KlL[d] + wKo) = kl4;
        *(uint2*)((char*)QhL[d] + wQo) = qh2;
        *(uint2*)((char*)QlL[d] + wQo) = ql2;
    };

    float m_all = -INFINITY;   // lane = j (0..63), redundant per wave
    float l_all = 0.0f;

    f32x4 Oacc[4][4];
    #pragma unroll
    for (int a = 0; a < 4; ++a)
        #pragma unroll
        for (int c = 0; c < 4; ++c) Oacc[a][c] = (f32x4)0.0f;

    load(ibase, 0);
    store(0);

    for (int ib = 0; ib < niblk; ++ib) {
        const int i0 = ibase + ib * IB;
        __syncthreads();   // buf0 (chunk 0) visible; Pt safe to rewrite later

        f32x4 Sacc[2][2];
        #pragma unroll
        for (int x = 0; x < 2; ++x)
            #pragma unroll
            for (int y = 0; y < 2; ++y) Sacc[x][y] = (f32x4)0.0f;

        // ---- phase A: S += K^T Q over 16 chunks, 1 barrier each ----
        for (int ck = 0; ck < NCH; ++ck) {
            const int d = ck & 1;
            if (ck + 1 < NCH) load(i0, (ck + 1) * KC);

            const char* kh = (const char*)KhL[d];
            const char* kl = (const char*)KlL[d];
            const char* qh = (const char*)QhL[d];
            const char* ql = (const char*)QlL[d];

            bf16x8 bqh[2], bql[2];
            #pragma unroll
            for (int jt = 0; jt < 2; ++jt) {
                bqh[jt] = *(const bf16x8*)(qh + offQ[jt]);
                bql[jt] = *(const bf16x8*)(ql + offQ[jt]);
            }
            __builtin_amdgcn_s_setprio(1);
            #pragma unroll
            for (int it = 0; it < 2; ++it) {
                const bf16x8 akh = *(const bf16x8*)(kh + offK[it]);
                const bf16x8 akl = *(const bf16x8*)(kl + offK[it]);
                #pragma unroll
                for (int jt = 0; jt < 2; ++jt) {
                    Sacc[it][jt] = __builtin_amdgcn_mfma_f32_16x16x32_bf16(akh, bqh[jt], Sacc[it][jt], 0, 0, 0);
                    Sacc[it][jt] = __builtin_amdgcn_mfma_f32_16x16x32_bf16(akh, bql[jt], Sacc[it][jt], 0, 0, 0);
                    Sacc[it][jt] = __builtin_amdgcn_mfma_f32_16x16x32_bf16(akl, bqh[jt], Sacc[it][jt], 0, 0, 0);
                }
            }
            __builtin_amdgcn_s_setprio(0);
            if (ck + 1 < NCH) {
                store(d ^ 1);
                __syncthreads();
            }
        }

        // ---- (a) per-column block max -> red_max ----
        #pragma unroll
        for (int jt = 0; jt < 2; ++jt) {
            float mx = -INFINITY;
            #pragma unroll
            for (int it = 0; it < 2; ++it)
                #pragma unroll
                for (int r = 0; r < 4; ++r) mx = fmaxf(mx, Sacc[it][jt][r]);
            mx = fmaxf(mx, __shfl_xor(mx, 16));
            mx = fmaxf(mx, __shfl_xor(mx, 32));
            if (lane < 16) red_max[iw][jw * 32 + jt * 16 + lane] = mx;
        }
        __syncthreads();   // bar1

        // ---- (b) redundant per-wave running max + scale (lane = j) ----
        float bm = fmaxf(fmaxf(red_max[0][lane], red_max[1][lane]),
                         fmaxf(red_max[2][lane], red_max[3][lane]));
        const float m_new = fmaxf(m_all, bm);
        const float scale = __expf(m_all - m_new);
        m_all = m_new;

        // ---- (c) exp, Pt write (swizzled), partial sums ----
        #pragma unroll
        for (int jt = 0; jt < 2; ++jt) {
            const int j = jw * 32 + jt * 16 + lr;
            const float mcol = __shfl(m_new, j);
            float csum = 0.0f;
            #pragma unroll
            for (int it = 0; it < 2; ++it) {
                const float p0 = __expf(Sacc[it][jt][0] - mcol);
                const float p1 = __expf(Sacc[it][jt][1] - mcol);
                const float p2 = __expf(Sacc[it][jt][2] - mcol);
                const float p3 = __expf(Sacc[it][jt][3] - mcol);
                csum += (p0 + p1) + (p2 + p3);
                ushort4 pk;
                pk.x = f2bf(p0); pk.y = f2bf(p1); pk.z = f2bf(p2); pk.w = f2bf(p3);
                const int i = iw * 32 + it * 16 + lg * 4;
                const unsigned byteoff =
                    ((unsigned)(j * (IB * 2) + i * 2)) ^ (((unsigned)(j & 7)) << 4);
                *(ushort4*)((char*)Pt + byteoff) = pk;
            }
            csum += __shfl_xor(csum, 16);
            csum += __shfl_xor(csum, 32);
            if (lane < 16) red_sum[iw][j] = csum;
        }
        // ---- O rescale (phase-B j mapping: j = jt*16+lr) ----
        {
            float scB[4];
            #pragma unroll
            for (int jt = 0; jt < 4; ++jt) scB[jt] = __shfl(scale, jt * 16 + lr);
            #pragma unroll
            for (int ct = 0; ct < 4; ++ct)
                #pragma unroll
                for (int jt = 0; jt < 4; ++jt) {
                    Oacc[ct][jt][0] *= scB[jt];
                    Oacc[ct][jt][1] *= scB[jt];
                    Oacc[ct][jt][2] *= scB[jt];
                    Oacc[ct][jt][3] *= scB[jt];
                }
        }
        __syncthreads();   // bar2: Pt + red_sum visible

        // ---- running denominator (redundant per wave, lane=j) ----
        l_all = l_all * scale +
                (red_sum[0][lane] + red_sum[1][lane]) +
                (red_sum[2][lane] + red_sum[3][lane]);

        // ---- phase B: Oacc += V_block * P; prefetch next i-block chunk 0 ----
        if (ib + 1 < niblk) load(i0 + IB, 0);
        {
            const int c0w = w * 64;
            #pragma unroll
            for (int ks = 0; ks < 4; ++ks) {
                bf16x8 pf[4];
                #pragma unroll
                for (int jt = 0; jt < 4; ++jt) {
                    const int j = jt * 16 + lr;
                    const unsigned byteoff =
                        ((unsigned)(j * (IB * 2) + ks * 64 + lg * 16)) ^ (((unsigned)(j & 7)) << 4);
                    pf[jt] = *(const bf16x8*)((char*)Pt + byteoff);
                }
                __builtin_amdgcn_s_setprio(1);
                #pragma unroll
                for (int ct = 0; ct < 4; ++ct) {
                    const int c = c0w + ct * 16 + lr;
                    const bf16x8 vf =
                        *(const bf16x8*)(Vh + ((size_t)(b * C_ + c)) * N_ + i0 + ks * 32 + lg * 8);
                    #pragma unroll
                    for (int jt = 0; jt < 4; ++jt)
                        Oacc[ct][jt] = __builtin_amdgcn_mfma_f32_16x16x32_bf16(vf, pf[jt], Oacc[ct][jt], 0, 0, 0);
                }
                __builtin_amdgcn_s_setprio(0);
            }
        }
        if (ib + 1 < niblk) store(0);
    }

    // ---- epilogue ----
    const int c0w = w * 64;
    if (nsplit == 1) {
        float il[4];
        #pragma unroll
        for (int jt = 0; jt < 4; ++jt) il[jt] = 1.0f / __shfl(l_all, jt * 16 + lr);
        #pragma unroll
        for (int ct = 0; ct < 4; ++ct) {
            #pragma unroll
            for (int r = 0; r < 4; ++r) {
                const int c = c0w + ct * 16 + lg * 4 + r;
                const float* qrow = Qorig + ((size_t)(b * C_ + c)) * N_ + j0;
                float*       orow = Out   + ((size_t)(b * C_ + c)) * N_ + j0;
                #pragma unroll
                for (int jt = 0; jt < 4; ++jt) {
                    const int j = jt * 16 + lr;
                    orow[j] = qrow[j] + Oacc[ct][jt][r] * il[jt];
                }
            }
        }
    } else {
        if (w == 0) {
            const size_t mb = ((size_t)(s * 256 + pj)) * 2 * 64;
            ml[mb + lane]      = m_all;
            ml[mb + 64 + lane] = l_all;
        }
        const size_t obase = ((size_t)(s * 256 + pj)) * (C_ * (size_t)JT);
        #pragma unroll
        for (int ct = 0; ct < 4; ++ct) {
            #pragma unroll
            for (int r = 0; r < 4; ++r) {
                const int c = c0w + ct * 16 + lg * 4 + r;
                #pragma unroll
                for (int jt = 0; jt < 4; ++jt)
                    Opart[obase + (size_t)c * JT + jt * 16 + lr] = f2bf(Oacc[ct][jt][r]);
            }
        }
    }
}

// ---------- combine two i-split partials ----------
__global__ __launch_bounds__(256)
void combine2(const unsigned short* __restrict__ Opart,
              const float* __restrict__ ml,
              const float* __restrict__ Qorig,
              float* __restrict__ Out)
{
    __shared__ float wi0[64], wi1[64];
    const int pj = (int)blockIdx.x;
    const int t  = (int)threadIdx.x;
    const int b  = pj >> 6;
    const int j0 = (pj & 63) * 64;
    if (t < 64) {
        const size_t m0b = ((size_t)pj) * 2 * 64;
        const size_t m1b = ((size_t)(256 + pj)) * 2 * 64;
        const float m0 = ml[m0b + t], l0 = ml[m0b + 64 + t];
        const float m1 = ml[m1b + t], l1 = ml[m1b + 64 + t];
        const float M  = fmaxf(m0, m1);
        const float w0 = __expf(m0 - M), w1 = __expf(m1 - M);
        const float den = w0 * l0 + w1 * l1;
        wi0[t] = w0 / den;
        wi1[t] = w1 / den;
    }
    __syncthreads();
    const size_t base0 = ((size_t)pj) * (C_ * 64);
    const size_t base1 = ((size_t)(256 + pj)) * (C_ * 64);
    #pragma unroll 4
    for (int rep = 0; rep < 16; ++rep) {
        const int task = rep * 256 + t;       // 0..4095
        const int c  = task >> 3;
        const int jg = (task & 7) * 8;
        const ushort4 a0 = *(const ushort4*)(Opart + base0 + (size_t)c * 64 + jg);
        const ushort4 a1 = *(const ushort4*)(Opart + base0 + (size_t)c * 64 + jg + 4);
        const ushort4 b0 = *(const ushort4*)(Opart + base1 + (size_t)c * 64 + jg);
        const ushort4 b1 = *(const ushort4*)(Opart + base1 + (size_t)c * 64 + jg + 4);
        const float* qp = Qorig + ((size_t)(b * C_ + c)) * N_ + j0 + jg;
        float*       op = Out   + ((size_t)(b * C_ + c)) * N_ + j0 + jg;
        op[0] = qp[0] + wi0[jg + 0] * bf2f(a0.x) + wi1[jg + 0] * bf2f(b0.x);
        op[1] = qp[1] + wi0[jg + 1] * bf2f(a0.y) + wi1[jg + 1] * bf2f(b0.y);
        op[2] = qp[2] + wi0[jg + 2] * bf2f(a0.z) + wi1[jg + 2] * bf2f(b0.z);
        op[3] = qp[3] + wi0[jg + 3] * bf2f(a0.w) + wi1[jg + 3] * bf2f(b0.w);
        op[4] = qp[4] + wi0[jg + 4] * bf2f(a1.x) + wi1[jg + 4] * bf2f(b1.x);
        op[5] = qp[5] + wi0[jg + 5] * bf2f(a1.y) + wi1[jg + 5] * bf2f(b1.y);
        op[6] = qp[6] + wi0[jg + 6] * bf2f(a1.z) + wi1[jg + 6] * bf2f(b1.z);
        op[7] = qp[7] + wi0[jg + 7] * bf2f(a1.w) + wi1[jg + 7] * bf2f(b1.w);
    }
}

// ---------- fallback (round-1 f32 kernel) if workspace is too small ----------
namespace {
constexpr int FJT = 32, FIB = 64, FTPB = 256, FNJT = N_ / FJT;
}
__global__ __launch_bounds__(FTPB, 2)
void attn_fused_f32(const float* __restrict__ Q,
                    const float* __restrict__ K,
                    const float* __restrict__ V,
                    float* __restrict__ O)
{
    __shared__ float q_lds[C_][FJT];
    __shared__ float p_t[FJT][FIB + 4];
    __shared__ float red_max[8][FJT];
    __shared__ float red_sum[8][FJT];

    const int t  = (int)threadIdx.x;
    const int j  = t & (FJT - 1);
    const int g  = t >> 5;
    const int b  = (int)blockIdx.x / FNJT;
    const int j0 = ((int)blockIdx.x % FNJT) * FJT;

    const float* Qb = Q + ((size_t)b * C_) * N_ + j0;
    const float* Kb = K + ((size_t)b * C_) * N_;
    const float* Vb = V + ((size_t)b * C_) * N_;
    float*       Ob = O + ((size_t)b * C_) * N_ + j0;

    #pragma unroll 4
    for (int r = 0; r < (C_ * FJT) / FTPB; ++r) {
        int idx = r * FTPB + t;
        q_lds[idx >> 5][idx & (FJT - 1)] = Qb[(size_t)(idx >> 5) * N_ + (idx & (FJT - 1))];
    }
    __syncthreads();

    float acc[64];
    #pragma unroll
    for (int x = 0; x < 64; ++x) acc[x] = 0.0f;
    float m_run = -INFINITY, l_run = 0.0f;

    for (int i0 = 0; i0 < N_; i0 += FIB) {
        float s_acc[8];
        #pragma unroll
        for (int r = 0; r < 8; ++r) s_acc[r] = 0.0f;
        const float* kp = Kb + i0 + g * 8;
        #pragma unroll 4
        for (int c = 0; c < C_; ++c) {
            float qv = q_lds[c][j];
            const float4 k0 = *(const float4*)(kp + (size_t)c * N_);
            const float4 k1 = *(const float4*)(kp + (size_t)c * N_ + 4);
            s_acc[0] = fmaf(k0.x, qv, s_acc[0]); s_acc[1] = fmaf(k0.y, qv, s_acc[1]);
            s_acc[2] = fmaf(k0.z, qv, s_acc[2]); s_acc[3] = fmaf(k0.w, qv, s_acc[3]);
            s_acc[4] = fmaf(k1.x, qv, s_acc[4]); s_acc[5] = fmaf(k1.y, qv, s_acc[5]);
            s_acc[6] = fmaf(k1.z, qv, s_acc[6]); s_acc[7] = fmaf(k1.w, qv, s_acc[7]);
        }
        float tmax = fmaxf(fmaxf(fmaxf(s_acc[0], s_acc[1]), fmaxf(s_acc[2], s_acc[3])),
                           fmaxf(fmaxf(s_acc[4], s_acc[5]), fmaxf(s_acc[6], s_acc[7])));
        red_max[g][j] = tmax;
        __syncthreads();
        float bmax = red_max[0][j];
        #pragma unroll
        for (int gg = 1; gg < 8; ++gg) bmax = fmaxf(bmax, red_max[gg][j]);
        float new_m = fmaxf(m_run, bmax);
        float scale = __expf(m_run - new_m);
        float psum = 0.0f, pv[8];
        #pragma unroll
        for (int r = 0; r < 8; ++r) { pv[r] = __expf(s_acc[r] - new_m); psum += pv[r]; }
        #pragma unroll
        for (int r = 0; r < 8; ++r) p_t[j][g * 8 + r] = pv[r];
        red_sum[g][j] = psum;
        __syncthreads();
        float bsum = 0.0f;
        #pragma unroll
        for (int gg = 0; gg < 8; ++gg) bsum += red_sum[gg][j];
        l_run = l_run * scale + bsum;
        m_run = new_m;
        #pragma unroll
        for (int x = 0; x < 64; ++x) acc[x] *= scale;
        const float* vp = Vb + (size_t)(g * 64) * N_ + i0;
        for (int i4 = 0; i4 < 16; ++i4) {
            const float4 p4 = *(const float4*)&p_t[j][i4 * 4];
            const float* vpi = vp + i4 * 4;
            #pragma unroll
            for (int cq = 0; cq < 4; ++cq) {
                #pragma unroll
                for (int ci = 0; ci < 16; ++ci) {
                    const int cc = cq * 16 + ci;
                    const float4 vv = *(const float4*)(vpi + (size_t)cc * N_);
                    acc[cc] = fmaf(vv.x, p4.x, acc[cc]);
                    acc[cc] = fmaf(vv.y, p4.y, acc[cc]);
                    acc[cc] = fmaf(vv.z, p4.z, acc[cc]);
                    acc[cc] = fmaf(vv.w, p4.w, acc[cc]);
                }
                asm volatile("" ::: "memory");
            }
        }
    }
    const float inv_l = 1.0f / l_run;
    #pragma unroll
    for (int cc = 0; cc < 64; ++cc) {
        const int c = g * 64 + cc;
        Ob[(size_t)c * N_ + j] = q_lds[c][j] + acc[cc] * inv_l;
    }
}

extern "C" void kernel_launch(void* const* d_in, const int* in_sizes, int n_in,
                              void* d_out, int out_size, void* d_ws, size_t ws_size,
                              hipStream_t stream) {
    const float* Q = (const float*)d_in[0];
    const float* K = (const float*)d_in[1];
    const float* V = (const float*)d_in[2];
    float* O = (float*)d_out;

    const size_t EL    = (size_t)B_ * C_ * N_;                 // 8388608
    const size_t NEED1 = EL * 2 * 5;                           // 80 MiB
    const size_t NEED2 = NEED1 + EL * 2 * 2 + 2 * 256 * 2 * 64 * sizeof(float);

    if (ws_size >= NEED1) {
        unsigned short* Kth = (unsigned short*)d_ws;
        unsigned short* Ktl = Kth + EL;
        unsigned short* Qth = Ktl + EL;
        unsigned short* Qtl = Qth + EL;
        unsigned short* Vhh = Qtl + EL;
        cvt_transpose_split<<<dim3(2048), dim3(256), 0, stream>>>(K, Kth, Ktl);
        cvt_transpose_split<<<dim3(2048), dim3(256), 0, stream>>>(Q, Qth, Qtl);
        cvt_split_hi<<<dim3(2048), dim3(256), 0, stream>>>(V, Vhh);
        if (ws_size >= NEED2) {
            unsigned short* Opart = Vhh + EL;
            float* ml = (float*)(Opart + 2 * EL);
            attn_mfma3<<<dim3(512), dim3(512), 0, stream>>>(
                Kth, Ktl, Qth, Qtl, Vhh, Q, O, Opart, ml, 2, NIB / 2);
            combine2<<<dim3(256), dim3(256), 0, stream>>>(Opart, ml, Q, O);
        } else {
            attn_mfma3<<<dim3(256), dim3(512), 0, stream>>>(
                Kth, Ktl, Qth, Qtl, Vhh, Q, O, nullptr, nullptr, 1, NIB);
        }
    } else {
        attn_fused_f32<<<dim3(B_ * FNJT), dim3(FTPB), 0, stream>>>(Q, K, V, O);
    }
}